// Round 12
// baseline (1845.786 us; speedup 1.0000x reference)
//
#include <hip/hip_runtime.h>
#include <math.h>

// Problem constants (reference: S,B,I,H = 1024,512,5,32; G=4H=128)
#define S_LEN 1024
#define BATCH 512
#define HID   32

#define LOG2E 1.44269504088896340736f

__device__ __forceinline__ float fast_rcp(float x) { return __builtin_amdgcn_rcpf(x); }
__device__ __forceinline__ float fast_exp2(float x) { return __builtin_amdgcn_exp2f(x); }

// gfx950 v_permlane32_swap_b32 with vdst = vsrc = v:
//   r[0] = value the HIGH half held, r[1] = value the LOW half held
typedef unsigned int uint2v __attribute__((ext_vector_type(2)));
__device__ __forceinline__ void swap_halves(float v, float& hiAll, float& loAll) {
    uint2v r = __builtin_amdgcn_permlane32_swap(__float_as_uint(v),
                                                __float_as_uint(v),
                                                false, false);
    hiAll = __uint_as_float(r[0]);
    loAll = __uint_as_float(r[1]);
}

// Broadcast lane k's value (k constant after unroll) -> SGPR operand.
__device__ __forceinline__ float bcast(float v, int k) {
    return __int_as_float(__builtin_amdgcn_readlane(__float_as_int(v), k));
}

// Full-wave (64-lane) sum via DPP — VALU-only (round-11: replaced the shfl
// chain, -118 us). Valid total lands in LANE 63.
__device__ __forceinline__ float wave_sum64_dpp(float v) {
    float s = v;
    s += __int_as_float(__builtin_amdgcn_update_dpp(
             0, __float_as_int(s), 0x111, 0xf, 0xf, true));   // row_shr:1
    s += __int_as_float(__builtin_amdgcn_update_dpp(
             0, __float_as_int(s), 0x112, 0xf, 0xf, true));   // row_shr:2
    s += __int_as_float(__builtin_amdgcn_update_dpp(
             0, __float_as_int(s), 0x114, 0xf, 0xf, true));   // row_shr:4
    s += __int_as_float(__builtin_amdgcn_update_dpp(
             0, __float_as_int(s), 0x118, 0xf, 0xf, true));   // row_shr:8
    s += __int_as_float(__builtin_amdgcn_update_dpp(
             0, __float_as_int(s), 0x142, 0xa, 0xf, true));   // row_bcast:15
    s += __int_as_float(__builtin_amdgcn_update_dpp(
             0, __float_as_int(s), 0x143, 0xc, 0xf, true));   // row_bcast:31
    return s;
}

// Load one 32-float weight row into registers, pre-scaled.
#define LOADROW(dst, base, row, sc)                                            \
    {                                                                          \
        const float4* W_ = reinterpret_cast<const float4*>((base) +            \
                                                    (size_t)(row) * HID);      \
        _Pragma("unroll")                                                      \
        for (int k4 = 0; k4 < 8; ++k4) {                                       \
            float4 v_ = W_[k4];                                                \
            dst[4 * k4 + 0] = v_.x * (sc);                                     \
            dst[4 * k4 + 1] = v_.y * (sc);                                     \
            dst[4 * k4 + 2] = v_.z * (sc);                                     \
            dst[4 * k4 + 3] = v_.w * (sc);                                     \
        }                                                                      \
    }

// SEQUENTIAL single-wave design: one wave per batch element computes all
// three layers PER STEP (natural LSTM dataflow: layer1 at step s consumes
// h0(s) computed moments earlier in the same wave).
//   - ZERO barriers, zero ring, zero pipeline skew, zero active-guards.
//   - 512 blocks x 64 threads = 512 waves (2/CU). Every stall is intra-wave;
//     3 interleavable layer-streams give the scheduler ILP to hide latency.
// Register plan (the 256-VGPR architected cliff killed rounds 2-3; lesson
// applied): ONLY whh0+whh1+wx in registers (~138 floats). The three
// LATE-NEEDED row-sets (Wih1, Wih2, Whh2) live in XOR-swizzled LDS (48 KB):
// their ds_read_b128 addresses are tick-invariant -> issued at tick start,
// consumed mid-tick = pure prefetch slack. Swizzle: float4-slot k4 ^ (row&7)
// spreads the 128B-stride rows across all banks (b128 floor).
// __launch_bounds__(64,1): round-3 evidence this unlocks the full 256-VGPR
// budget (vs the allocator's default 4-waves/EU squeeze to ~100).
// Cross-lane: readlane broadcasts (VALU), permlane32 half-exchange, DPP
// reduce for the collapsed-MLP output (v = 0.5*W1^T W2^T w3, round-10/11).
// Weights/biases pre-scaled by log2e (g rows by 2*log2e): activation is the
// uniform sigma(y)=rcp(1+exp2(-y)); tanh(g)=2*sigma(2g)-1.
__global__ __launch_bounds__(64, 1)
void lstm3_seq(const float* __restrict__ x,
               const float* __restrict__ Wih0, const float* __restrict__ Whh0,
               const float* __restrict__ bih0, const float* __restrict__ bhh0,
               const float* __restrict__ Wih1, const float* __restrict__ Whh1,
               const float* __restrict__ bih1, const float* __restrict__ bhh1,
               const float* __restrict__ Wih2, const float* __restrict__ Whh2,
               const float* __restrict__ bih2, const float* __restrict__ bhh2,
               const float* __restrict__ w1, const float* __restrict__ b1,
               const float* __restrict__ w2, const float* __restrict__ b2,
               const float* __restrict__ w3, const float* __restrict__ b3,
               float* __restrict__ out)
{
    const int b = blockIdx.x;
    const int l = threadIdx.x & 63;
    const int j = l & 31;
    const bool lowHalf = (l < 32);
    const int gA = l;
    const int gB = l + 64;
    const int andA = l & 7;           // swizzle key, same for gA and gB
    const float sA = LOG2E;
    const float sB = lowHalf ? (2.0f * LOG2E) : LOG2E;

    // LDS weight sets: [0]=Wih1, [1]=Wih2, [2]=Whh2; 128 rows x 32 floats,
    // float4-slot swizzled by (k4 ^ (row&7)). 48 KB.
    __shared__ float wlds[3 * 128 * 32];

    // ---- one-time staging (single wave: ds in-order, NO barrier needed) ----
    for (int i4 = l; i4 < 3 * 1024; i4 += 64) {
        const int set = i4 >> 10;
        const int rem = i4 & 1023;
        const int row = rem >> 3;
        const int k4  = rem & 7;
        const float* W = (set == 0) ? Wih1 : (set == 1) ? Wih2 : Whh2;
        float4 v = *reinterpret_cast<const float4*>(W + row * HID + k4 * 4);
        const float sc = (row >= 64 && row < 96) ? 2.0f * LOG2E : LOG2E;
        v.x *= sc; v.y *= sc; v.z *= sc; v.w *= sc;
        *reinterpret_cast<float4*>(
            &wlds[(set << 12) + row * HID + ((k4 ^ (row & 7)) << 2)]) = v;
    }

    // ---- register-resident weights: whh0, whh1, wx (early-needed) ----
    float whA0[HID], whB0[HID], whA1[HID], whB1[HID];
    LOADROW(whA0, Whh0, gA, sA); LOADROW(whB0, Whh0, gB, sB);
    LOADROW(whA1, Whh1, gA, sA); LOADROW(whB1, Whh1, gB, sB);
    float wxA[5], wxB[5];
#pragma unroll
    for (int k = 0; k < 5; ++k) {
        wxA[k] = Wih0[gA * 5 + k] * sA;
        wxB[k] = Wih0[gB * 5 + k] * sB;
    }
    const float b0A = (bih0[gA] + bhh0[gA]) * sA;
    const float b0B = (bih0[gB] + bhh0[gB]) * sB;
    const float b1A = (bih1[gA] + bhh1[gA]) * sA;
    const float b1B = (bih1[gB] + bhh1[gB]) * sB;
    const float b2A = (bih2[gA] + bhh2[gA]) * sA;
    const float b2B = (bih2[gB] + bhh2[gB]) * sB;

    // ---- collapsed MLP: v_j (x0.5 for the 64-lane DPP sum) and cbias ----
    float v_j = 0.0f, cbias = 0.0f;
    {
        float uacc[HID];
#pragma unroll
        for (int k = 0; k < HID; ++k) uacc[k] = 0.0f;
        for (int r = 0; r < HID; ++r) {         // u = w3^T W2 (uniform loads)
            const float w3r = w3[r];
#pragma unroll
            for (int k = 0; k < HID; ++k)
                uacc[k] += w3r * w2[r * HID + k];
        }
#pragma unroll
        for (int k = 0; k < HID; ++k) {
            v_j   += uacc[k] * w1[k * HID + j];
            cbias += uacc[k] * b1[k];
        }
        for (int r = 0; r < HID; ++r) cbias += w3[r] * b2[r];
        cbias += b3[0];
        v_j *= 0.5f;    // halves replicated -> 64-lane sum double-counts
    }

    float h0 = 0.f, h1 = 0.f, h2 = 0.f, c0 = 0.f, c1 = 0.f, c2 = 0.f;

    const float* xb = x + (size_t)b * 5;
    float xv0 = xb[0], xv1 = xb[1], xv2 = xb[2], xv3 = xb[3], xv4 = xb[4];

    // LDS matvec: 8 swizzled b128 pairs x broadcast h -> 64 FMA.
#define MATVEC_LDS(setbase, hsrc, A0, A1, A2, A3, B0, B1, B2, B3)              \
    _Pragma("unroll")                                                          \
    for (int k4 = 0; k4 < 8; ++k4) {                                           \
        const int perm = ((k4 ^ andA) << 2);                                   \
        const float4 wa = *reinterpret_cast<const float4*>(                    \
            &wlds[(setbase) + gA * HID + perm]);                               \
        const float4 wb = *reinterpret_cast<const float4*>(                    \
            &wlds[(setbase) + gB * HID + perm]);                               \
        const float hh0 = bcast(hsrc, 4 * k4 + 0);                             \
        const float hh1 = bcast(hsrc, 4 * k4 + 1);                             \
        const float hh2 = bcast(hsrc, 4 * k4 + 2);                             \
        const float hh3 = bcast(hsrc, 4 * k4 + 3);                             \
        A0 += wa.x * hh0; A1 += wa.y * hh1;                                    \
        A2 += wa.z * hh2; A3 += wa.w * hh3;                                    \
        B0 += wb.x * hh0; B1 += wb.y * hh1;                                    \
        B2 += wb.z * hh2; B3 += wb.w * hh3;                                    \
    }

    // Register matvec: weight array x broadcast h.
#define MATVEC_REG(WA, WB, hsrc, A0, A1, A2, A3, B0, B1, B2, B3)               \
    _Pragma("unroll")                                                          \
    for (int k4 = 0; k4 < 8; ++k4) {                                           \
        const float hh0 = bcast(hsrc, 4 * k4 + 0);                             \
        const float hh1 = bcast(hsrc, 4 * k4 + 1);                             \
        const float hh2 = bcast(hsrc, 4 * k4 + 2);                             \
        const float hh3 = bcast(hsrc, 4 * k4 + 3);                             \
        A0 += WA[4 * k4 + 0] * hh0; A1 += WA[4 * k4 + 1] * hh1;                \
        A2 += WA[4 * k4 + 2] * hh2; A3 += WA[4 * k4 + 3] * hh3;                \
        B0 += WB[4 * k4 + 0] * hh0; B1 += WB[4 * k4 + 1] * hh1;                \
        B2 += WB[4 * k4 + 2] * hh2; B3 += WB[4 * k4 + 3] * hh3;                \
    }

    // LSTM pointwise tail (permlane half-exchange + uniform sigma).
#define TAIL(A0, A1, A2, A3, B0, B1, B2, B3, cvar, hvar)                       \
    {                                                                          \
        const float accA = ((A0) + (A1)) + ((A2) + (A3));                      \
        const float accB = ((B0) + (B1)) + ((B2) + (B3));                      \
        float yf, yi, yo, yg;                                                  \
        swap_halves(accA, yf, yi);                                             \
        swap_halves(accB, yo, yg);                                             \
        const float gi = fast_rcp(1.0f + fast_exp2(-yi));                      \
        const float gf = fast_rcp(1.0f + fast_exp2(-yf));                      \
        const float sg = fast_rcp(1.0f + fast_exp2(-yg));                      \
        const float go = fast_rcp(1.0f + fast_exp2(-yo));                      \
        const float gg = 2.0f * sg - 1.0f;                                     \
        const float cn = gf * (cvar) + gi * gg;                                \
        const float e_ = fast_exp2(-2.0f * LOG2E * fabsf(cn));                 \
        const float tc = copysignf((1.0f - e_) * fast_rcp(1.0f + e_), cn);     \
        (cvar) = cn;                                                           \
        (hvar) = go * tc;                                                      \
    }

#pragma unroll 1
    for (int t = 0; t < S_LEN; ++t) {
        // layer-0 accumulators (x input + recurrent, all reg-resident)
        float a0A0 = b0A, a0A1 = 0.f, a0A2 = 0.f, a0A3 = 0.f;
        float a0B0 = b0B, a0B1 = 0.f, a0B2 = 0.f, a0B3 = 0.f;
        a0A0 += wxA[0] * xv0; a0B0 += wxB[0] * xv0;
        a0A1 += wxA[1] * xv1; a0B1 += wxB[1] * xv1;
        a0A2 += wxA[2] * xv2; a0B2 += wxB[2] * xv2;
        a0A3 += wxA[3] * xv3; a0B3 += wxB[3] * xv3;
        a0A0 += wxA[4] * xv4; a0B0 += wxB[4] * xv4;
        MATVEC_REG(whA0, whB0, h0, a0A0, a0A1, a0A2, a0A3,
                                   a0B0, a0B1, a0B2, a0B3);

        // layer-1 recurrent (reg weights, h1(t-1)) — independent of tail0
        float a1A0 = b1A, a1A1 = 0.f, a1A2 = 0.f, a1A3 = 0.f;
        float a1B0 = b1B, a1B1 = 0.f, a1B2 = 0.f, a1B3 = 0.f;
        MATVEC_REG(whA1, whB1, h1, a1A0, a1A1, a1A2, a1A3,
                                   a1B0, a1B1, a1B2, a1B3);

        // layer-2 recurrent (LDS weights, h2(t-1)) — also independent
        float a2A0 = b2A, a2A1 = 0.f, a2A2 = 0.f, a2A3 = 0.f;
        float a2B0 = b2B, a2B1 = 0.f, a2B2 = 0.f, a2B3 = 0.f;
        MATVEC_LDS(2 << 12, h2, a2A0, a2A1, a2A2, a2A3,
                                a2B0, a2B1, a2B2, a2B3);

        // prefetch next x (consumed next tick; never stalls this one)
        if (t + 1 < S_LEN) {
            const float* xn = xb + (size_t)(t + 1) * (BATCH * 5);
            xv0 = xn[0]; xv1 = xn[1]; xv2 = xn[2]; xv3 = xn[3]; xv4 = xn[4];
        }

        // layer 0 finish -> h0(t)
        TAIL(a0A0, a0A1, a0A2, a0A3, a0B0, a0B1, a0B2, a0B3, c0, h0);

        // layer-1 input (LDS Wih1 x fresh h0(t))
        MATVEC_LDS(0 << 12, h0, a1A0, a1A1, a1A2, a1A3,
                                a1B0, a1B1, a1B2, a1B3);
        TAIL(a1A0, a1A1, a1A2, a1A3, a1B0, a1B1, a1B2, a1B3, c1, h1);

        // layer-2 input (LDS Wih2 x fresh h1(t))
        MATVEC_LDS(1 << 12, h1, a2A0, a2A1, a2A2, a2A3,
                                a2B0, a2B1, a2B2, a2B3);
        TAIL(a2A0, a2A1, a2A2, a2A3, a2B0, a2B1, a2B2, a2B3, c2, h2);

        // collapsed MLP: y = relu(v.h2 + cbias); VALU-only DPP reduce
        const float tot = wave_sum64_dpp(h2 * v_j);
        const float y = fmaxf(tot + cbias, 0.0f);
        if (l == 63)
            out[(size_t)t * BATCH + b] = y;     // streamed, never waited
    }
#undef MATVEC_LDS
#undef MATVEC_REG
#undef TAIL
}

extern "C" void kernel_launch(void* const* d_in, const int* in_sizes, int n_in,
                              void* d_out, int out_size, void* d_ws, size_t ws_size,
                              hipStream_t stream)
{
    const float* x    = (const float*)d_in[0];
    const float* Wih0 = (const float*)d_in[1];
    const float* Whh0 = (const float*)d_in[2];
    const float* bih0 = (const float*)d_in[3];
    const float* bhh0 = (const float*)d_in[4];
    const float* Wih1 = (const float*)d_in[5];
    const float* Whh1 = (const float*)d_in[6];
    const float* bih1 = (const float*)d_in[7];
    const float* bhh1 = (const float*)d_in[8];
    const float* Wih2 = (const float*)d_in[9];
    const float* Whh2 = (const float*)d_in[10];
    const float* bih2 = (const float*)d_in[11];
    const float* bhh2 = (const float*)d_in[12];
    const float* w1   = (const float*)d_in[13];
    const float* b1   = (const float*)d_in[14];
    const float* w2   = (const float*)d_in[15];
    const float* b2   = (const float*)d_in[16];
    const float* w3   = (const float*)d_in[17];
    const float* b3   = (const float*)d_in[18];

    lstm3_seq<<<BATCH, 64, 0, stream>>>(x, Wih0, Whh0, bih0, bhh0,
                                        Wih1, Whh1, bih1, bhh1,
                                        Wih2, Whh2, bih2, bhh2,
                                        w1, b1, w2, b2, w3, b3,
                                        (float*)d_out);
}

// Round 13
// 1011.835 us; speedup vs baseline: 1.8242x; 1.8242x over previous
//
#include <hip/hip_runtime.h>
#include <math.h>

// Problem constants (reference: S,B,I,H = 1024,512,5,32; G=4H=128)
#define S_LEN 1024
#define BATCH 512
#define HID   32

#define LOG2E 1.44269504088896340736f

__device__ __forceinline__ float fast_rcp(float x) { return __builtin_amdgcn_rcpf(x); }
__device__ __forceinline__ float fast_exp2(float x) { return __builtin_amdgcn_exp2f(x); }

// Barrier WITHOUT vmcnt drain (out stores stream; never waited in-loop).
__device__ __forceinline__ void tick_barrier() {
    asm volatile("s_waitcnt lgkmcnt(0)" ::: "memory");
    __builtin_amdgcn_s_barrier();
    asm volatile("" ::: "memory");   // compiler fence: no LDS op hoisted above
}

// gfx950 v_permlane32_swap_b32 with vdst = vsrc = v:
//   r[0] = value the HIGH half held, r[1] = value the LOW half held
typedef unsigned int uint2v __attribute__((ext_vector_type(2)));
__device__ __forceinline__ void swap_halves(float v, float& hiAll, float& loAll) {
    uint2v r = __builtin_amdgcn_permlane32_swap(__float_as_uint(v),
                                                __float_as_uint(v),
                                                false, false);
    hiAll = __uint_as_float(r[0]);
    loAll = __uint_as_float(r[1]);
}

// Broadcast lane k's value (k constant after unroll) -> SGPR operand.
__device__ __forceinline__ float bcast(float v, int k) {
    return __int_as_float(__builtin_amdgcn_readlane(__float_as_int(v), k));
}

// Full-wave (64-lane) sum via DPP — VALU-only (round-11: -118 us vs shfl).
// Valid total lands in LANE 63.
__device__ __forceinline__ float wave_sum64_dpp(float v) {
    float s = v;
    s += __int_as_float(__builtin_amdgcn_update_dpp(
             0, __float_as_int(s), 0x111, 0xf, 0xf, true));   // row_shr:1
    s += __int_as_float(__builtin_amdgcn_update_dpp(
             0, __float_as_int(s), 0x112, 0xf, 0xf, true));   // row_shr:2
    s += __int_as_float(__builtin_amdgcn_update_dpp(
             0, __float_as_int(s), 0x114, 0xf, 0xf, true));   // row_shr:4
    s += __int_as_float(__builtin_amdgcn_update_dpp(
             0, __float_as_int(s), 0x118, 0xf, 0xf, true));   // row_shr:8
    s += __int_as_float(__builtin_amdgcn_update_dpp(
             0, __float_as_int(s), 0x142, 0xa, 0xf, true));   // row_bcast:15
    s += __int_as_float(__builtin_amdgcn_update_dpp(
             0, __float_as_int(s), 0x143, 0xc, 0xf, true));   // row_bcast:31
    return s;
}

// Load one 32-float weight row into registers, pre-scaled.
#define LOADROW(dst, base, row, sc)                                            \
    {                                                                          \
        const float4* W_ = reinterpret_cast<const float4*>((base) +            \
                                                    (size_t)(row) * HID);      \
        _Pragma("unroll")                                                      \
        for (int k4 = 0; k4 < 8; ++k4) {                                       \
            float4 v_ = W_[k4];                                                \
            dst[4 * k4 + 0] = v_.x * (sc);                                     \
            dst[4 * k4 + 1] = v_.y * (sc);                                     \
            dst[4 * k4 + 2] = v_.z * (sc);                                     \
            dst[4 * k4 + 3] = v_.w * (sc);                                     \
        }                                                                      \
    }

// Fused 3-layer LSTM + collapsed MLP head (round-11 skeleton, proven best:
// 3 structural rewrites — 6-wave split, 1-wave-register, 1-wave-sequential —
// all lost to it). Block = 192 threads = 3 waves; wave w = layer w;
// blockIdx = batch element; 512 blocks = 2 blocks/CU co-resident.
//
// LAG-4 + FUSED QUAD BODY (this round's change): wave w processes
// s = t - 4w; ring depth 8 (writer slot t&7, reader (t&7)^4 = written 4
// ticks ago, previous quad); ONE lgkmcnt-only barrier per FOUR ticks
// (258 vs R11's 513). The 4-tick body exposes cross-tick ILP the single-tick
// loop could not: all four input matvecs (ring/x) are legal at quad start,
// and each tail(u)'s ~100-cyc serial chain (permlane-exp2-rcp-tanh) is
// interleaved with the independent input-matvec(u+1) FMA stream.
// Peak extra live = 2 ticks' accumulators (+16 regs) -> ~165 VGPR, under the
// 256 2-waves/SIMD cliff (round-9 lesson); waves_per_eu(2) pins it.
//
// MLP COLLAPSE: y = relu(v.h2 + cbias), v = 0.5*W1^T(W2^T w3) (the 0.5
// compensates the 64-lane DPP sum double-counting replicated halves).
// Lane l owns rows gA=l, gB=l+64 (torch order i,f,g,o); pre-scaled by log2e
// (g rows by 2*log2e): activation is uniform sigma(y)=rcp(1+exp2(-y));
// tanh(g)=2*sigma(2g)-1. x block-slice staged in LDS once.
__global__ __launch_bounds__(192)
__attribute__((amdgpu_waves_per_eu(2)))
void lstm3_fused(const float* __restrict__ x,
                 const float* __restrict__ Wih0, const float* __restrict__ Whh0,
                 const float* __restrict__ bih0, const float* __restrict__ bhh0,
                 const float* __restrict__ Wih1, const float* __restrict__ Whh1,
                 const float* __restrict__ bih1, const float* __restrict__ bhh1,
                 const float* __restrict__ Wih2, const float* __restrict__ Whh2,
                 const float* __restrict__ bih2, const float* __restrict__ bhh2,
                 const float* __restrict__ w1, const float* __restrict__ b1,
                 const float* __restrict__ w2, const float* __restrict__ b2,
                 const float* __restrict__ w3, const float* __restrict__ b3,
                 float* __restrict__ out)
{
    const int b = blockIdx.x;
    const int w = threadIdx.x >> 6;   // wave id == layer id, 0..2
    const int l = threadIdx.x & 63;
    const int j = l & 31;
    const bool lowHalf = (l < 32);
    const int gA = l;
    const int gB = l + 64;
    const float sA = LOG2E;
    const float sB = lowHalf ? (2.0f * LOG2E) : LOG2E;  // g rows get 2*log2e

    // x slice: xl4[s] = x[s][b][0..3], xl1[s] = x[s][b][4]
    __shared__ float4 xl4[S_LEN];     // 16 KB
    __shared__ float  xl1[S_LEN];     //  4 KB
    // ring[slot][src_wave][unit]; slot = tick & 7 (lag-4, depth-8). 2 KB.
    __shared__ float ring[8][2][HID];

    for (int i = threadIdx.x; i < 8 * 2 * HID; i += 192)
        (&ring[0][0][0])[i] = 0.0f;
    {
        float* xf = reinterpret_cast<float*>(xl4);
        for (int idx = threadIdx.x; idx < S_LEN * 5; idx += 192) {
            const int s = idx / 5;
            const int c = idx - 5 * s;
            const float v = x[(size_t)s * (BATCH * 5) + b * 5 + c];
            if (c < 4) xf[s * 4 + c] = v;
            else       xl1[s] = v;
        }
    }

    const float* Wih = (w == 0) ? Wih0 : (w == 1) ? Wih1 : Wih2;
    const float* Whh = (w == 0) ? Whh0 : (w == 1) ? Whh1 : Whh2;
    const float* bih = (w == 0) ? bih0 : (w == 1) ? bih1 : bih2;
    const float* bhh = (w == 0) ? bhh0 : (w == 1) ? bhh1 : bhh2;

    // Recurrent weight rows in registers (all waves), pre-scaled
    float whA[HID], whB[HID];
    LOADROW(whA, Whh, gA, sA);
    LOADROW(whB, Whh, gB, sB);
    // Input weight rows: wave 0 has KIN=5, waves 1/2 have KIN=32.
    float wiA[HID], wiB[HID];
    float wxA[5], wxB[5];
    if (w == 0) {
#pragma unroll
        for (int k = 0; k < 5; ++k) {
            wxA[k] = Wih[gA * 5 + k] * sA;
            wxB[k] = Wih[gB * 5 + k] * sB;
        }
    } else {
        LOADROW(wiA, Wih, gA, sA);
        LOADROW(wiB, Wih, gB, sB);
    }
    const float biasA = (bih[gA] + bhh[gA]) * sA;
    const float biasB = (bih[gB] + bhh[gB]) * sB;

    // Collapsed MLP: v_j (x0.5 for the 64-lane DPP sum) and cbias (wave 2)
    float v_j = 0.0f, cbias = 0.0f;
    if (w == 2) {
        float uacc[HID];
#pragma unroll
        for (int k = 0; k < HID; ++k) uacc[k] = 0.0f;
        for (int r = 0; r < HID; ++r) {         // u = w3^T W2 (uniform loads)
            const float w3r = w3[r];
#pragma unroll
            for (int k = 0; k < HID; ++k)
                uacc[k] += w3r * w2[r * HID + k];
        }
#pragma unroll
        for (int k = 0; k < HID; ++k) {
            v_j   += uacc[k] * w1[k * HID + j];
            cbias += uacc[k] * b1[k];
        }
        for (int r = 0; r < HID; ++r) cbias += w3[r] * b2[r];
        cbias += b3[0];
        v_j *= 0.5f;    // halves replicated -> 64-lane sum double-counts
    }

    float c = 0.0f;
    float h_own = 0.0f;   // own-layer h(t-1), unit j, identical in both halves

    __syncthreads();  // staging + ring init visible (one-time full barrier)

// ---- per-tick building blocks (token-pasted names keep all indices static)
#define TICK_INIT(n)                                                           \
    float aA0_##n = biasA, aA1_##n = 0.f, aA2_##n = 0.f, aA3_##n = 0.f;        \
    float aB0_##n = biasB, aB1_##n = 0.f, aB2_##n = 0.f, aB3_##n = 0.f;

#define TICK_INPUT(n, tt)                                                      \
    if (w == 0) {                                                              \
        if ((tt) < S_LEN) {                                                    \
            const float4 xv = xl4[(tt)];                                       \
            const float  x4 = xl1[(tt)];                                       \
            aA0_##n += wxA[0] * xv.x; aB0_##n += wxB[0] * xv.x;                \
            aA1_##n += wxA[1] * xv.y; aB1_##n += wxB[1] * xv.y;                \
            aA2_##n += wxA[2] * xv.z; aB2_##n += wxB[2] * xv.z;                \
            aA3_##n += wxA[3] * xv.w; aB3_##n += wxB[3] * xv.w;                \
            aA0_##n += wxA[4] * x4;   aB0_##n += wxB[4] * x4;                  \
        }                                                                      \
    } else {                                                                   \
        const float4* hin4 =                                                   \
            reinterpret_cast<const float4*>(&ring[((tt) & 7) ^ 4][w - 1][0]);  \
        _Pragma("unroll")                                                      \
        for (int k4 = 0; k4 < 8; ++k4) {                                       \
            const float4 hv = hin4[k4];                                        \
            aA0_##n += wiA[4 * k4 + 0] * hv.x;                                 \
            aA1_##n += wiA[4 * k4 + 1] * hv.y;                                 \
            aA2_##n += wiA[4 * k4 + 2] * hv.z;                                 \
            aA3_##n += wiA[4 * k4 + 3] * hv.w;                                 \
            aB0_##n += wiB[4 * k4 + 0] * hv.x;                                 \
            aB1_##n += wiB[4 * k4 + 1] * hv.y;                                 \
            aB2_##n += wiB[4 * k4 + 2] * hv.z;                                 \
            aB3_##n += wiB[4 * k4 + 3] * hv.w;                                 \
        }                                                                      \
    }

#define TICK_OWN(n)                                                            \
    _Pragma("unroll")                                                          \
    for (int k4 = 0; k4 < 8; ++k4) {                                           \
        const float h0_ = bcast(h_own, 4 * k4 + 0);                            \
        const float h1_ = bcast(h_own, 4 * k4 + 1);                            \
        const float h2_ = bcast(h_own, 4 * k4 + 2);                            \
        const float h3_ = bcast(h_own, 4 * k4 + 3);                            \
        aA0_##n += whA[4 * k4 + 0] * h0_;                                      \
        aA1_##n += whA[4 * k4 + 1] * h1_;                                      \
        aA2_##n += whA[4 * k4 + 2] * h2_;                                      \
        aA3_##n += whA[4 * k4 + 3] * h3_;                                      \
        aB0_##n += whB[4 * k4 + 0] * h0_;                                      \
        aB1_##n += whB[4 * k4 + 1] * h1_;                                      \
        aB2_##n += whB[4 * k4 + 2] * h2_;                                      \
        aB3_##n += whB[4 * k4 + 3] * h3_;                                      \
    }

#define TICK_TAIL(n, tt)                                                       \
    {                                                                          \
        const int s_ = (tt) - 4 * w;                                           \
        const bool act_ = (s_ >= 0) && (s_ < S_LEN);                           \
        const float accA = (aA0_##n + aA1_##n) + (aA2_##n + aA3_##n);          \
        const float accB = (aB0_##n + aB1_##n) + (aB2_##n + aB3_##n);          \
        float yf, yi, yo, yg;                                                  \
        swap_halves(accA, yf, yi);                                             \
        swap_halves(accB, yo, yg);                                             \
        const float gi = fast_rcp(1.0f + fast_exp2(-yi));                      \
        const float gf = fast_rcp(1.0f + fast_exp2(-yf));                      \
        const float sg = fast_rcp(1.0f + fast_exp2(-yg));                      \
        const float go = fast_rcp(1.0f + fast_exp2(-yo));                      \
        const float gg = 2.0f * sg - 1.0f;                                     \
        const float cn = gf * c + gi * gg;                                     \
        const float e_ = fast_exp2(-2.0f * LOG2E * fabsf(cn));                 \
        const float tc = copysignf((1.0f - e_) * fast_rcp(1.0f + e_), cn);     \
        const float hh = go * tc;                                              \
        if (act_) {                                                            \
            c = cn;                                                            \
            h_own = hh;                                                        \
            if (w < 2) {                                                       \
                if (lowHalf) ring[(tt) & 7][w][j] = hh;                        \
            } else {                                                           \
                const float tot = wave_sum64_dpp(hh * v_j);                    \
                const float y = fmaxf(tot + cbias, 0.0f);                      \
                if (l == 63) out[(size_t)s_ * BATCH + b] = y;                  \
            }                                                                  \
        }                                                                      \
    }

#pragma unroll 1
    for (int t = 0; t < S_LEN + 8; t += 4) {
        // Quad body: inputs hoisted (all legal at quad start, lag-4 ring);
        // each tail's serial chain overlaps the next tick's input matvec.
        TICK_INIT(0) TICK_INPUT(0, t + 0)
        TICK_OWN(0)
        TICK_INIT(1) TICK_INPUT(1, t + 1)
        TICK_TAIL(0, t + 0)
        TICK_OWN(1)
        TICK_INIT(2) TICK_INPUT(2, t + 2)
        TICK_TAIL(1, t + 1)
        TICK_OWN(2)
        TICK_INIT(3) TICK_INPUT(3, t + 3)
        TICK_TAIL(2, t + 2)
        TICK_OWN(3)
        TICK_TAIL(3, t + 3)
        tick_barrier();   // ONE lgkmcnt-only barrier per QUAD
    }
#undef TICK_INIT
#undef TICK_INPUT
#undef TICK_OWN
#undef TICK_TAIL
}

extern "C" void kernel_launch(void* const* d_in, const int* in_sizes, int n_in,
                              void* d_out, int out_size, void* d_ws, size_t ws_size,
                              hipStream_t stream)
{
    const float* x    = (const float*)d_in[0];
    const float* Wih0 = (const float*)d_in[1];
    const float* Whh0 = (const float*)d_in[2];
    const float* bih0 = (const float*)d_in[3];
    const float* bhh0 = (const float*)d_in[4];
    const float* Wih1 = (const float*)d_in[5];
    const float* Whh1 = (const float*)d_in[6];
    const float* bih1 = (const float*)d_in[7];
    const float* bhh1 = (const float*)d_in[8];
    const float* Wih2 = (const float*)d_in[9];
    const float* Whh2 = (const float*)d_in[10];
    const float* bih2 = (const float*)d_in[11];
    const float* bhh2 = (const float*)d_in[12];
    const float* w1   = (const float*)d_in[13];
    const float* b1   = (const float*)d_in[14];
    const float* w2   = (const float*)d_in[15];
    const float* b2   = (const float*)d_in[16];
    const float* w3   = (const float*)d_in[17];
    const float* b3   = (const float*)d_in[18];

    lstm3_fused<<<BATCH, 192, 0, stream>>>(x, Wih0, Whh0, bih0, bhh0,
                                           Wih1, Whh1, bih1, bhh1,
                                           Wih2, Whh2, bih2, bhh2,
                                           w1, b1, w2, b2, w3, b3,
                                           (float*)d_out);
}

// Round 14
// 897.324 us; speedup vs baseline: 2.0570x; 1.1276x over previous
//
#include <hip/hip_runtime.h>
#include <math.h>

// Problem constants (reference: S,B,I,H = 1024,512,5,32; G=4H=128)
#define S_LEN 1024
#define BATCH 512
#define HID   32

#define LOG2E 1.44269504088896340736f

typedef float float2v __attribute__((ext_vector_type(2)));

__device__ __forceinline__ float fast_rcp(float x) { return __builtin_amdgcn_rcpf(x); }
__device__ __forceinline__ float fast_exp2(float x) { return __builtin_amdgcn_exp2f(x); }

// Barrier WITHOUT vmcnt drain (out stores stream; never waited in-loop).
__device__ __forceinline__ void tick_barrier() {
    asm volatile("s_waitcnt lgkmcnt(0)" ::: "memory");
    __builtin_amdgcn_s_barrier();
    asm volatile("" ::: "memory");   // compiler fence: no LDS op hoisted above
}

// gfx950 v_permlane32_swap_b32 with vdst = vsrc = v:
//   r[0] = value the HIGH half held, r[1] = value the LOW half held
typedef unsigned int uint2v __attribute__((ext_vector_type(2)));
__device__ __forceinline__ void swap_halves(float v, float& hiAll, float& loAll) {
    uint2v r = __builtin_amdgcn_permlane32_swap(__float_as_uint(v),
                                                __float_as_uint(v),
                                                false, false);
    hiAll = __uint_as_float(r[0]);
    loAll = __uint_as_float(r[1]);
}

// Broadcast lane k's value (k constant after unroll) -> SGPR operand.
__device__ __forceinline__ float bcast(float v, int k) {
    return __int_as_float(__builtin_amdgcn_readlane(__float_as_int(v), k));
}

// Full-wave (64-lane) sum via DPP — VALU-only (round-11: -118 us vs shfl).
// Valid total lands in LANE 63.
__device__ __forceinline__ float wave_sum64_dpp(float v) {
    float s = v;
    s += __int_as_float(__builtin_amdgcn_update_dpp(
             0, __float_as_int(s), 0x111, 0xf, 0xf, true));   // row_shr:1
    s += __int_as_float(__builtin_amdgcn_update_dpp(
             0, __float_as_int(s), 0x112, 0xf, 0xf, true));   // row_shr:2
    s += __int_as_float(__builtin_amdgcn_update_dpp(
             0, __float_as_int(s), 0x114, 0xf, 0xf, true));   // row_shr:4
    s += __int_as_float(__builtin_amdgcn_update_dpp(
             0, __float_as_int(s), 0x118, 0xf, 0xf, true));   // row_shr:8
    s += __int_as_float(__builtin_amdgcn_update_dpp(
             0, __float_as_int(s), 0x142, 0xa, 0xf, true));   // row_bcast:15
    s += __int_as_float(__builtin_amdgcn_update_dpp(
             0, __float_as_int(s), 0x143, 0xc, 0xf, true));   // row_bcast:31
    return s;
}

// Load rows gA (x-lane) and gB (y-lane) of a [G x HID] matrix into a PACKED
// float2 array, pre-scaled per lane-half: dst[k] = {W[rA][k]*scA, W[rB][k]*scB}.
// Packed A/B rows share every broadcast multiplicand -> v_pk_fma_f32 halves
// the matvec instruction count (round-14 lever).
#define LOADROW_PK(dst, base, rA, rB, scA_, scB_)                              \
    {                                                                          \
        const float4* WA_ = reinterpret_cast<const float4*>((base) +           \
                                                    (size_t)(rA) * HID);       \
        const float4* WB_ = reinterpret_cast<const float4*>((base) +           \
                                                    (size_t)(rB) * HID);       \
        _Pragma("unroll")                                                      \
        for (int k4 = 0; k4 < 8; ++k4) {                                       \
            float4 va_ = WA_[k4];                                              \
            float4 vb_ = WB_[k4];                                              \
            dst[4 * k4 + 0] = (float2v){va_.x * (scA_), vb_.x * (scB_)};       \
            dst[4 * k4 + 1] = (float2v){va_.y * (scA_), vb_.y * (scB_)};       \
            dst[4 * k4 + 2] = (float2v){va_.z * (scA_), vb_.z * (scB_)};       \
            dst[4 * k4 + 3] = (float2v){va_.w * (scA_), vb_.w * (scB_)};       \
        }                                                                      \
    }

// Fused 3-layer LSTM + collapsed MLP head — round-11 skeleton (proven best
// across 6 structural alternatives), with PACKED-FP32 matvecs.
// Block = 192 threads = 3 waves; wave w = layer w; blockIdx = batch element;
// 512 blocks = 2 blocks/CU co-resident (cross-block overlap hides stalls;
// t-loop stays unroll-1 and waves_per_eu(2) pins regs under the 256 cliff —
// round-9/13 lessons: fatter bodies lose).
//
// LAG-2 PIPELINE: wave w processes s = t - 2w; ring depth 4 (writer t&3,
// reader (t&3)^2); ONE lgkmcnt-only barrier per tick-pair.
//
// PACKED MATH (this round): each lane's two gate rows (gA=l, gB=l+64) are
// stored interleaved as float2; acc is 4 packed chains. Every FMA pairs the
// A-row and B-row against the same broadcast h -> v_pk_fma_f32 (VOP3P),
// halving matvec issue: 128 FMA -> 64 pk-FMA per heavy wave per tick.
//
// MLP COLLAPSE: y = relu(v.h2 + cbias), v = 0.5*W1^T(W2^T w3); VALU-only DPP
// reduce; store from lane 63, never waited.
// Lane l owns rows gA=l, gB=l+64 (torch order i,f,g,o); pre-scaled by log2e
// (g rows by 2*log2e): activation is uniform sigma(y)=rcp(1+exp2(-y));
// tanh(g)=2*sigma(2g)-1. x block-slice staged in LDS once.
__global__ __launch_bounds__(192)
__attribute__((amdgpu_waves_per_eu(2)))
void lstm3_fused(const float* __restrict__ x,
                 const float* __restrict__ Wih0, const float* __restrict__ Whh0,
                 const float* __restrict__ bih0, const float* __restrict__ bhh0,
                 const float* __restrict__ Wih1, const float* __restrict__ Whh1,
                 const float* __restrict__ bih1, const float* __restrict__ bhh1,
                 const float* __restrict__ Wih2, const float* __restrict__ Whh2,
                 const float* __restrict__ bih2, const float* __restrict__ bhh2,
                 const float* __restrict__ w1, const float* __restrict__ b1,
                 const float* __restrict__ w2, const float* __restrict__ b2,
                 const float* __restrict__ w3, const float* __restrict__ b3,
                 float* __restrict__ out)
{
    const int b = blockIdx.x;
    const int w = threadIdx.x >> 6;   // wave id == layer id, 0..2
    const int l = threadIdx.x & 63;
    const int j = l & 31;
    const int gA = l;
    const int gB = l + 64;
    const float sA = LOG2E;
    const float sB = (l < 32) ? (2.0f * LOG2E) : LOG2E;  // g rows get 2*log2e

    // x slice: xl4[s] = x[s][b][0..3], xl1[s] = x[s][b][4]
    __shared__ float4 xl4[S_LEN];     // 16 KB
    __shared__ float  xl1[S_LEN];     //  4 KB
    // ring[slot][src_wave][unit]; slot = tick & 3 (lag-2, depth-4)
    __shared__ float ring[4][2][HID];

    for (int i = threadIdx.x; i < 4 * 2 * HID; i += 192)
        (&ring[0][0][0])[i] = 0.0f;
    {
        float* xf = reinterpret_cast<float*>(xl4);
        for (int idx = threadIdx.x; idx < S_LEN * 5; idx += 192) {
            const int s = idx / 5;
            const int c = idx - 5 * s;
            const float v = x[(size_t)s * (BATCH * 5) + b * 5 + c];
            if (c < 4) xf[s * 4 + c] = v;
            else       xl1[s] = v;
        }
    }

    const float* Wih = (w == 0) ? Wih0 : (w == 1) ? Wih1 : Wih2;
    const float* Whh = (w == 0) ? Whh0 : (w == 1) ? Whh1 : Whh2;
    const float* bih = (w == 0) ? bih0 : (w == 1) ? bih1 : bih2;
    const float* bhh = (w == 0) ? bhh0 : (w == 1) ? bhh1 : bhh2;

    // Recurrent weight rows, PACKED (all waves), pre-scaled
    float2v whP[HID];
    LOADROW_PK(whP, Whh, gA, gB, sA, sB);
    // Input weight rows: wave 0 has KIN=5, waves 1/2 have KIN=32 (packed).
    float2v wiP[HID];
    float2v wxP[5];
    if (w == 0) {
#pragma unroll
        for (int k = 0; k < 5; ++k)
            wxP[k] = (float2v){Wih[gA * 5 + k] * sA, Wih[gB * 5 + k] * sB};
    } else {
        LOADROW_PK(wiP, Wih, gA, gB, sA, sB);
    }
    const float2v biasP = {(bih[gA] + bhh[gA]) * sA,
                           (bih[gB] + bhh[gB]) * sB};

    // Collapsed MLP: v_j (x0.5 for the 64-lane DPP sum) and cbias (wave 2)
    float v_j = 0.0f, cbias = 0.0f;
    if (w == 2) {
        float uacc[HID];
#pragma unroll
        for (int k = 0; k < HID; ++k) uacc[k] = 0.0f;
        for (int r = 0; r < HID; ++r) {         // u = w3^T W2 (uniform loads)
            const float w3r = w3[r];
#pragma unroll
            for (int k = 0; k < HID; ++k)
                uacc[k] += w3r * w2[r * HID + k];
        }
#pragma unroll
        for (int k = 0; k < HID; ++k) {
            v_j   += uacc[k] * w1[k * HID + j];
            cbias += uacc[k] * b1[k];
        }
        for (int r = 0; r < HID; ++r) cbias += w3[r] * b2[r];
        cbias += b3[0];
        v_j *= 0.5f;    // halves replicated -> 64-lane sum double-counts
    }

    float c = 0.0f;
    float h_own = 0.0f;   // own-layer h(t-1), unit j, identical in both halves

    __syncthreads();  // staging + ring init visible (one-time full barrier)

#pragma unroll 1
    for (int t = 0; t < S_LEN + 4; ++t) {
        const int s = t - 2 * w;
        const bool active = (s >= 0) && (s < S_LEN);
        const int wslot = t & 3;
        const int rslot = wslot ^ 2;   // written 2 ticks ago (previous pair)

        // ---- gate matvecs, packed: acc = bias + Whh*h_own + Wih*input ----
        float2v aP0 = biasP;
        float2v aP1 = {0.f, 0.f};
        float2v aP2 = {0.f, 0.f};
        float2v aP3 = {0.f, 0.f};

        // own h via readlane broadcast (register-only, no LDS)
#pragma unroll
        for (int k4 = 0; k4 < HID / 4; ++k4) {
            const float h0 = bcast(h_own, 4 * k4 + 0);
            const float h1 = bcast(h_own, 4 * k4 + 1);
            const float h2 = bcast(h_own, 4 * k4 + 2);
            const float h3 = bcast(h_own, 4 * k4 + 3);
            aP0 += whP[4 * k4 + 0] * (float2v){h0, h0};
            aP1 += whP[4 * k4 + 1] * (float2v){h1, h1};
            aP2 += whP[4 * k4 + 2] * (float2v){h2, h2};
            aP3 += whP[4 * k4 + 3] * (float2v){h3, h3};
        }

        if (w == 0) {
            if (active) {   // wave-uniform branch
                const float4 xv = xl4[s];
                const float  x4 = xl1[s];
                aP0 += wxP[0] * (float2v){xv.x, xv.x};
                aP1 += wxP[1] * (float2v){xv.y, xv.y};
                aP2 += wxP[2] * (float2v){xv.z, xv.z};
                aP3 += wxP[3] * (float2v){xv.w, xv.w};
                aP0 += wxP[4] * (float2v){x4, x4};
            }
        } else {
            // input = previous layer's h from ring (broadcast b128 reads)
            const float4* hin4 =
                reinterpret_cast<const float4*>(&ring[rslot][w - 1][0]);
#pragma unroll
            for (int k4 = 0; k4 < HID / 4; ++k4) {
                const float4 hv = hin4[k4];
                aP0 += wiP[4 * k4 + 0] * (float2v){hv.x, hv.x};
                aP1 += wiP[4 * k4 + 1] * (float2v){hv.y, hv.y};
                aP2 += wiP[4 * k4 + 2] * (float2v){hv.z, hv.z};
                aP3 += wiP[4 * k4 + 3] * (float2v){hv.w, hv.w};
            }
        }
        const float2v aP = (aP0 + aP1) + (aP2 + aP3);
        const float accA = aP.x;
        const float accB = aP.y;

        // ---- half-exchange: all lanes get all 4 gates of unit j ----
        float yf, yi, yo, yg;
        swap_halves(accA, yf, yi);   // low half held i, high half held f
        swap_halves(accB, yo, yg);   // low half held g, high half held o

        const float gi = fast_rcp(1.0f + fast_exp2(-yi));
        const float gf = fast_rcp(1.0f + fast_exp2(-yf));
        const float sg = fast_rcp(1.0f + fast_exp2(-yg));
        const float go = fast_rcp(1.0f + fast_exp2(-yo));
        const float gg = 2.0f * sg - 1.0f;      // tanh(g) = 2*sigma(2g) - 1

        const float c_new = gf * c + gi * gg;
        const float e  = fast_exp2(-2.0f * LOG2E * fabsf(c_new));
        const float tc = copysignf((1.0f - e) * fast_rcp(1.0f + e), c_new);
        const float h = go * tc;                // identical in both halves

        if (active) {
            c = c_new;
            h_own = h;                          // stays in registers
            if (w < 2) {
                if (l < 32) ring[wslot][w][j] = h;    // for layer w+1, t+2
            } else {
                // collapsed MLP: y = relu(v.h + cbias), VALU-only DPP reduce
                const float tot = wave_sum64_dpp(h * v_j);
                const float y = fmaxf(tot + cbias, 0.0f);
                if (l == 63)
                    out[(size_t)s * BATCH + b] = y;   // streamed, unwaited
            }
        }
        if (t & 1) tick_barrier();   // ONE barrier per tick-pair
    }
}

extern "C" void kernel_launch(void* const* d_in, const int* in_sizes, int n_in,
                              void* d_out, int out_size, void* d_ws, size_t ws_size,
                              hipStream_t stream)
{
    const float* x    = (const float*)d_in[0];
    const float* Wih0 = (const float*)d_in[1];
    const float* Whh0 = (const float*)d_in[2];
    const float* bih0 = (const float*)d_in[3];
    const float* bhh0 = (const float*)d_in[4];
    const float* Wih1 = (const float*)d_in[5];
    const float* Whh1 = (const float*)d_in[6];
    const float* bih1 = (const float*)d_in[7];
    const float* bhh1 = (const float*)d_in[8];
    const float* Wih2 = (const float*)d_in[9];
    const float* Whh2 = (const float*)d_in[10];
    const float* bih2 = (const float*)d_in[11];
    const float* bhh2 = (const float*)d_in[12];
    const float* w1   = (const float*)d_in[13];
    const float* b1   = (const float*)d_in[14];
    const float* w2   = (const float*)d_in[15];
    const float* b2   = (const float*)d_in[16];
    const float* w3   = (const float*)d_in[17];
    const float* b3   = (const float*)d_in[18];

    lstm3_fused<<<BATCH, 192, 0, stream>>>(x, Wih0, Whh0, bih0, bhh0,
                                           Wih1, Whh1, bih1, bhh1,
                                           Wih2, Whh2, bih2, bhh2,
                                           w1, b1, w2, b2, w3, b3,
                                           (float*)d_out);
}